// Round 3
// baseline (283.995 us; speedup 1.0000x reference)
//
#include <hip/hip_runtime.h>
#include <hip/hip_bf16.h>

typedef unsigned short u16;
typedef __attribute__((ext_vector_type(8))) short short8;
typedef __attribute__((ext_vector_type(4))) float floatx4;

#define B_SZ 4
#define T_SZ 2048
#define C_SZ 1024
#define NH_SZ 16
#define HD_SZ 64
#define M_TOT 8192      // B*T
#define K_DIM 1024      // C

// fold softmax 1/sqrt(64) and log2(e) into Q's affine: scores land in log2 domain
#define QSCALE 0.1803368801111204f   // 0.125 * 1.4426950408889634

// workspace layout (u16 element offsets from ws base; all 16B-aligned)
#define OFF_XB   ((size_t)16)
#define OFF_WQT  (OFF_XB + 8388608)
#define OFF_WPT  (OFF_WQT + 3145728)
#define OFF_PB   (OFF_WPT + 1048576)
#define OFF_Q    (OFF_PB + 8192)
#define OFF_K    (OFF_Q + 8388608)
#define OFF_V    (OFF_K + 8388608)
#define OFF_Y    (OFF_V + 8388608)
// params sub-layout inside PB (contiguous: sources in order)
#define PB_BQKV  0
#define PB_BPROJ 3072
#define PB_QSC   4096
#define PB_QBI   5120
#define PB_KSC   6144
#define PB_KBI   7168

__device__ __forceinline__ float bf2f(u16 u) {
    return __uint_as_float(((unsigned)u) << 16);
}
__device__ __forceinline__ u16 f2bf(float f) {          // round-nearest-even
    unsigned x = __float_as_uint(f);
    unsigned r = (x + 0x7fffu + ((x >> 16) & 1u)) >> 16;
    return (u16)r;
}
__device__ __forceinline__ u16 f2bf_fast(float f) {     // round-half-up (cheap)
    return (u16)((__float_as_uint(f) + 0x8000u) >> 16);
}
// pack two f32 -> u32 of two bf16 (T12 recipe; no builtin on gfx950)
__device__ __forceinline__ unsigned cvt_pk_bf16(float lo, float hi) {
    unsigned r;
    asm("v_cvt_pk_bf16_f32 %0, %1, %2" : "=v"(r) : "v"(lo), "v"(hi));
    return r;
}
// async global->LDS, 16B per lane; LDS dest = wave-uniform base + lane*16
__device__ __forceinline__ void gl_lds16(const u16* g, u16* l) {
    __builtin_amdgcn_global_load_lds(
        (const __attribute__((address_space(1))) void*)g,
        (__attribute__((address_space(3))) void*)l, 16, 0, 0);
}
// wave-uniform dtype detect from x[0:128] u16 (deterministic across blocks)
__device__ __forceinline__ int detect_isf(const u16* xx, int lane) {
    float v0 = fabsf(bf2f(xx[lane * 2]));
    float v1 = fabsf(bf2f(xx[lane * 2 + 1]));
    int b0 = (v0 > 1024.0f) || (v0 != 0.0f && v0 < 9.5367431640625e-7f);
    int b1 = (v1 > 1024.0f) || (v1 != 0.0f && v1 < 9.5367431640625e-7f);
    unsigned long long ba = __ballot(b0), bb = __ballot(b1);
    return (__popcll(ba) + __popcll(bb)) > 8;
}

// ---- unified prep: x copy + params pack + both weight transposes ----------
__global__ __launch_bounds__(256) void prep_k(
        const void* __restrict__ x,
        const void* __restrict__ Wqkv, const void* __restrict__ Wproj,
        const void* __restrict__ bqkv, const void* __restrict__ bproj,
        const void* __restrict__ qsc, const void* __restrict__ qbi,
        const void* __restrict__ ksc, const void* __restrict__ kbi,
        u16* __restrict__ xb, u16* __restrict__ Wt_qkv,
        u16* __restrict__ Wt_proj, u16* __restrict__ pb,
        int* __restrict__ flag) {
    __shared__ u16 t[32][33];
    const int blk = blockIdx.x;
    const int isf = detect_isf((const u16*)x, threadIdx.x & 63);
    if (blk == 0 && threadIdx.x == 0) flag[0] = isf;
    if (blk < 8192) {                       // x -> xb (4 elems/thread)
        const int i = blk * 256 + threadIdx.x;
        if (isf) {
            const float4 v = ((const float4*)x)[i];
            ushort4 o;
            o.x = f2bf(v.x); o.y = f2bf(v.y); o.z = f2bf(v.z); o.w = f2bf(v.w);
            ((ushort4*)xb)[i] = o;
        } else {
            ((ushort4*)xb)[i] = ((const ushort4*)x)[i];
        }
        return;
    }
    if (blk < 8200) {                       // small params -> pb
        const int i4 = (blk - 8192) * 256 + threadIdx.x;
        if (i4 >= 2048) return;
        const int e = i4 * 4;
        const void* src; int off;
        if (e < 3072)      { src = bqkv;  off = e; }
        else if (e < 4096) { src = bproj; off = e - 3072; }
        else if (e < 5120) { src = qsc;   off = e - 4096; }
        else if (e < 6144) { src = qbi;   off = e - 5120; }
        else if (e < 7168) { src = ksc;   off = e - 6144; }
        else               { src = kbi;   off = e - 7168; }
        ushort4 o;
        if (isf) {
            const float4 v = *(const float4*)((const float*)src + off);
            o.x = f2bf(v.x); o.y = f2bf(v.y); o.z = f2bf(v.z); o.w = f2bf(v.w);
        } else {
            o = *(const ushort4*)((const u16*)src + off);
        }
        *(ushort4*)&pb[e] = o;
        return;
    }
    const void* in; u16* out; int R, C, idx;
    if (blk < 11272) { idx = blk - 8200;  in = Wqkv;  out = Wt_qkv;  R = 1024; C = 3072; }
    else             { idx = blk - 11272; in = Wproj; out = Wt_proj; R = 1024; C = 1024; }
    const int nbx = C >> 5;
    const int c0 = (idx % nbx) * 32, r0 = (idx / nbx) * 32;
    const int tx = threadIdx.x & 31, ty = threadIdx.x >> 5;  // ty in 0..7
    for (int i = 0; i < 4; i++) {
        int r = ty + i * 8;
        size_t gi = (size_t)(r0 + r) * C + c0 + tx;
        t[r][tx] = isf ? f2bf(((const float*)in)[gi]) : ((const u16*)in)[gi];
    }
    __syncthreads();
    for (int i = 0; i < 4; i++) {
        int cr = ty + i * 8;
        out[(size_t)(c0 + cr) * R + r0 + tx] = t[tx][cr];
    }
}

// ---------------- QKV GEMM: 128x192 tile, dbuf LDS (80KB -> 2 blocks/CU) ---
// 8 waves (2M x 4N), per-wave 64x48. Per K-tile per wave: 5 gl_lds (2 A + 3 B)
// -> steady-state guard s_waitcnt vmcnt(5).
#define QG_BM 128
#define QG_BN 192
#define QG_NT 16

__global__ __launch_bounds__(512, 4) void qkv_gemm(
        const u16* __restrict__ X, const u16* __restrict__ Wt,
        const u16* __restrict__ pb,
        u16* __restrict__ Qb, u16* __restrict__ Kb, u16* __restrict__ Vb) {
    __shared__ __align__(16) u16 As[2][QG_BM * 64];   // 32 KB
    __shared__ __align__(16) u16 Bs[2][QG_BN * 64];   // 48 KB
    const int bm = blockIdx.y * QG_BM, bn = blockIdx.x * QG_BN;
    const int tid = threadIdx.x;
    const int lane = tid & 63, w = tid >> 6;
    const int quad = lane >> 4, l16 = lane & 15;
    const int wm = (w >> 2) * 64;         // 0 or 64
    const int wn = (w & 3) * 48;          // 0,48,96,144
    const int lrow = lane >> 3;                       // 8 rows per inst
    const int lcol = ((lane & 7) ^ lrow) * 8;         // swizzled source chunk
    const int sl0 = ((0 + quad) ^ (l16 & 7)) * 8;     // kk = 0
    const int sl1 = ((4 + quad) ^ (l16 & 7)) * 8;     // kk = 32

#define QG_STAGE(slot, kt) do {                                                  \
        const int k0_ = (kt) * 64;                                               \
        _Pragma("unroll")                                                        \
        for (int j = 0; j < 2; j++) {                                            \
            const int rb = w * 16 + j * 8;                                       \
            gl_lds16(&X[(size_t)(bm + rb + lrow) * K_DIM + k0_ + lcol],          \
                     &As[slot][rb * 64]);                                        \
        }                                                                        \
        _Pragma("unroll")                                                        \
        for (int j = 0; j < 3; j++) {                                            \
            const int rb = w * 24 + j * 8;                                       \
            gl_lds16(&Wt[(size_t)(bn + rb + lrow) * K_DIM + k0_ + lcol],         \
                     &Bs[slot][rb * 64]);                                        \
        }                                                                        \
    } while (0)

    floatx4 acc[4][3];
#pragma unroll
    for (int mi = 0; mi < 4; mi++)
#pragma unroll
        for (int ni = 0; ni < 3; ni++) acc[mi][ni] = 0.f;

    // prologue: tiles 0 and 1 in flight; wait tile 0 (5 of tile 1 may remain)
    QG_STAGE(0, 0);
    QG_STAGE(1, 1);
    asm volatile("s_waitcnt vmcnt(5)" ::: "memory");
    __builtin_amdgcn_s_barrier();

    for (int t = 0; t < QG_NT; ++t) {
        const int cur = t & 1;
        const u16* as = As[cur];
        const u16* bs = Bs[cur];
        short8 a[4], b[3];
        // phase A: kk = 0
#pragma unroll
        for (int mi = 0; mi < 4; mi++)
            a[mi] = *(const short8*)&as[(wm + mi * 16 + l16) * 64 + sl0];
#pragma unroll
        for (int ni = 0; ni < 3; ni++)
            b[ni] = *(const short8*)&bs[(wn + ni * 16 + l16) * 64 + sl0];
        __builtin_amdgcn_s_setprio(1);
#pragma unroll
        for (int mi = 0; mi < 4; mi++)
#pragma unroll
            for (int ni = 0; ni < 3; ni++)
                acc[mi][ni] = __builtin_amdgcn_mfma_f32_16x16x32_bf16(
                    a[mi], b[ni], acc[mi][ni], 0, 0, 0);
        __builtin_amdgcn_s_setprio(0);
        // phase B reads: kk = 32
#pragma unroll
        for (int mi = 0; mi < 4; mi++)
            a[mi] = *(const short8*)&as[(wm + mi * 16 + l16) * 64 + sl1];
#pragma unroll
        for (int ni = 0; ni < 3; ni++)
            b[ni] = *(const short8*)&bs[(wn + ni * 16 + l16) * 64 + sl1];
        // all of this wave's reads of buf[cur] complete -> barrier -> overwrite
        asm volatile("s_waitcnt lgkmcnt(0)" ::: "memory");
        __builtin_amdgcn_s_barrier();
        if (t < QG_NT - 1) {
            const int tn = (t + 2 < QG_NT) ? t + 2 : QG_NT - 1;  // redundant at
            QG_STAGE(cur, tn);        // t=NT-2 keeps vmcnt accounting uniform
        }
        __builtin_amdgcn_s_setprio(1);
#pragma unroll
        for (int mi = 0; mi < 4; mi++)
#pragma unroll
            for (int ni = 0; ni < 3; ni++)
                acc[mi][ni] = __builtin_amdgcn_mfma_f32_16x16x32_bf16(
                    a[mi], b[ni], acc[mi][ni], 0, 0, 0);
        __builtin_amdgcn_s_setprio(0);
        // tile t+1 landed (only tile t+2's 5 loads may remain outstanding)
        asm volatile("s_waitcnt vmcnt(5)" ::: "memory");
        __builtin_amdgcn_s_barrier();
    }
#undef QG_STAGE

    const int bb = bm >> 11;   // batch index (BM=128 never crosses T=2048)
    const int tbase = bm & 2047;
#pragma unroll
    for (int ni = 0; ni < 3; ni++) {
        const int col = bn + wn + ni * 16 + l16;
        const int sec = col >> 10;          // wave-uniform per fragment
        const int cmod = col & 1023;
        const int h = cmod >> 6, d = cmod & 63;
        const float bv = bf2f(pb[PB_BQKV + col]);
        if (sec == 2) {
#pragma unroll
            for (int mi = 0; mi < 4; mi++) {
                const int t0 = tbase + wm + mi * 16 + quad * 4;
                ushort4 pk;
                pk.x = f2bf(acc[mi][ni][0] + bv);
                pk.y = f2bf(acc[mi][ni][1] + bv);
                pk.z = f2bf(acc[mi][ni][2] + bv);
                pk.w = f2bf(acc[mi][ni][3] + bv);
                *(ushort4*)&Vb[(((size_t)(bb * NH_SZ + h)) * HD_SZ + d) * T_SZ + t0] = pk;
            }
        } else {
            float sA, sB;
            if (sec == 0) {
                sA = bf2f(pb[PB_QSC + h * 64 + d]) * QSCALE;
                sB = bf2f(pb[PB_QBI + h * 64 + d]) * QSCALE;
            } else {
                sA = bf2f(pb[PB_KSC + h * 64 + d]);
                sB = bf2f(pb[PB_KBI + h * 64 + d]);
            }
            u16* dstbuf = (sec == 0) ? Qb : Kb;
#pragma unroll
            for (int mi = 0; mi < 4; mi++)
#pragma unroll
                for (int r = 0; r < 4; r++) {
                    const int tt = tbase + wm + mi * 16 + quad * 4 + r;
                    float v = (acc[mi][ni][r] + bv) * sA + sB;
                    dstbuf[(((size_t)(bb * NH_SZ + h)) * T_SZ + tt) * HD_SZ + d] = f2bf(v);
                }
        }
    }
}

// -------- Flash attention: dbuf K/V + counted vmcnt, 51.2KB LDS (3 blk/CU) -
__global__ __launch_bounds__(512, 6) void attn_k(const u16* __restrict__ Qb,
                                                 const u16* __restrict__ Kb,
                                                 const u16* __restrict__ Vtg,
                                                 u16* __restrict__ Y) {
    __shared__ __align__(16) u16 Ks[2][64 * 64];    // [key][d], swizzled chunks
    __shared__ __align__(16) u16 Vs[2][64 * 64];    // [d][key], swizzled chunks
    __shared__ __align__(16) u16 Ps[8 * 16 * 72];   // per-wave P^T [q][key], stride 72
    const int blk = blockIdx.x;
    const int head = blk & 63;          // b*NH + h
    const int p = blk >> 6;             // pair index 0..7
    const int b = head >> 4, h = head & 15;
    const int tid = threadIdx.x, lane = tid & 63, w = tid >> 6;
    const int quad = lane >> 4, l16 = lane & 15;
    const size_t qk_off = (size_t)head * (T_SZ * HD_SZ);
    const size_t v_off = (size_t)head * (HD_SZ * T_SZ);
    u16* psw = &Ps[w * 1152];           // wave-private P^T region
    const int lr = lane >> 3;                     // staging row within wave group
    const int lc = ((lane & 7) ^ lr) * 8;         // swizzled source chunk
    const int sl0 = ((quad) ^ (l16 & 7)) * 8;         // kk = 0
    const int sl1 = ((4 + quad) ^ (l16 & 7)) * 8;     // kk = 32

    short8 ones;
    for (int j = 0; j < 8; j++) ones[j] = (short)0x3F80;  // bf16 1.0

    for (int tile = 0; tile < 2; tile++) {
        const int qt = tile ? p : (15 - p);
        const int q0 = qt * 128;
        const int rbase = q0 + w * 16;  // wave's first q row
        const int q = rbase + l16;      // this lane's q row
        const int nt = (q0 >> 6) + 2;   // k-tiles for this q-tile

        const short8 aq0 = *(const short8*)&Qb[qk_off + (size_t)q * HD_SZ + quad * 8];
        const short8 aq1 = *(const short8*)&Qb[qk_off + (size_t)q * HD_SZ + 32 + quad * 8];

        floatx4 o[4];                   // o^T: col=q(lane), rows=d-group mi
        for (int mi = 0; mi < 4; mi++) o[mi] = 0.f;
        float m_run = -1e30f, l_run = 0.f;

        // prologue: stage tile 0 into buf 0 (2 loads/wave in flight)
        gl_lds16(&Kb[qk_off + (size_t)(w * 8 + lr) * HD_SZ + lc], &Ks[0][w * 512]);
        gl_lds16(&Vtg[v_off + (size_t)(w * 8 + lr) * T_SZ + lc], &Vs[0][w * 512]);

        for (int t = 0; t < nt; ++t) {
            const int cur = t & 1;
            const int k0 = t * 64;
            if (t + 1 < nt) {           // prefetch tile t+1 into other buffer
                const int kn = k0 + 64;
                gl_lds16(&Kb[qk_off + (size_t)(kn + w * 8 + lr) * HD_SZ + lc],
                         &Ks[cur ^ 1][w * 512]);
                gl_lds16(&Vtg[v_off + (size_t)(w * 8 + lr) * T_SZ + kn + lc],
                         &Vs[cur ^ 1][w * 512]);
                // tile t landed; tile t+1's 2 loads may remain outstanding
                asm volatile("s_waitcnt vmcnt(2)" ::: "memory");
            } else {
                asm volatile("s_waitcnt vmcnt(0)" ::: "memory");
            }
            __builtin_amdgcn_s_barrier();

            if (k0 <= rbase + 15) {     // not fully masked for this wave
                const u16* ks = Ks[cur];
                const u16* vs = Vs[cur];
                floatx4 s[4];
                for (int ni = 0; ni < 4; ni++) s[ni] = 0.f;
                __builtin_amdgcn_s_setprio(1);
                for (int ni = 0; ni < 4; ni++)
                    s[ni] = __builtin_amdgcn_mfma_f32_16x16x32_bf16(
                        *(const short8*)&ks[(ni * 16 + l16) * 64 + sl0], aq0, s[ni], 0, 0, 0);
                for (int ni = 0; ni < 4; ni++)
                    s[ni] = __builtin_amdgcn_mfma_f32_16x16x32_bf16(
                        *(const short8*)&ks[(ni * 16 + l16) * 64 + sl1], aq1, s[ni], 0, 0, 0);
                __builtin_amdgcn_s_setprio(0);

                if (k0 + 63 > rbase) {          // tile touches the diagonal
                    for (int ni = 0; ni < 4; ni++)
                        for (int r = 0; r < 4; r++) {
                            int key = k0 + ni * 16 + quad * 4 + r;
                            if (key > q) s[ni][r] = -1e30f;
                        }
                }

                // 3-ary max tree (fuses to v_max3_f32)
                float t0 = fmaxf(fmaxf(s[0][0], s[0][1]), s[0][2]);
                float t1 = fmaxf(fmaxf(s[0][3], s[1][0]), s[1][1]);
                float t2 = fmaxf(fmaxf(s[1][2], s[1][3]), s[2][0]);
                float t3 = fmaxf(fmaxf(s[2][1], s[2][2]), s[2][3]);
                float t4 = fmaxf(fmaxf(s[3][0], s[3][1]), s[3][2]);
                float mx = fmaxf(fmaxf(fmaxf(t0, t1), fmaxf(t2, t3)),
                                 fmaxf(t4, s[3][3]));
                mx = fmaxf(mx, __shfl_xor(mx, 16, 64));
                mx = fmaxf(mx, __shfl_xor(mx, 32, 64));

                // defer-max (T13): skip rescale while max drift <= 8 (log2 units)
                if (!__all(mx <= m_run + 8.0f)) {
                    const float mnew = fmaxf(m_run, mx);
                    const float alpha = exp2f(m_run - mnew);
                    m_run = mnew;
                    for (int mi = 0; mi < 4; mi++) o[mi] *= alpha;
                    l_run *= alpha;
                }
                for (int ni = 0; ni < 4; ni++)
                    for (int r = 0; r < 4; r++)
                        s[ni][r] = exp2f(s[ni][r] - m_run);

                for (int ni = 0; ni < 4; ni++) {
                    uint2 pp;
                    pp.x = cvt_pk_bf16(s[ni][0], s[ni][1]);
                    pp.y = cvt_pk_bf16(s[ni][2], s[ni][3]);
                    *(uint2*)&psw[l16 * 72 + ni * 16 + quad * 4] = pp;
                }

                floatx4 s4 = 0.f;
                __builtin_amdgcn_s_setprio(1);
                for (int kk = 0; kk < 64; kk += 32) {
                    short8 pfr = *(const short8*)&psw[l16 * 72 + kk + quad * 8];
                    const int vsl = (kk == 0) ? sl0 : sl1;
                    s4 = __builtin_amdgcn_mfma_f32_16x16x32_bf16(ones, pfr, s4, 0, 0, 0);
                    for (int mi = 0; mi < 4; mi++) {
                        short8 vfr = *(const short8*)&vs[(mi * 16 + l16) * 64 + vsl];
                        o[mi] = __builtin_amdgcn_mfma_f32_16x16x32_bf16(vfr, pfr, o[mi], 0, 0, 0);
                    }
                }
                __builtin_amdgcn_s_setprio(0);
                l_run += s4[0];
            }
            // all LDS reads of buf[cur] done before next iter's stage overwrites
            asm volatile("s_waitcnt lgkmcnt(0)" ::: "memory");
            __builtin_amdgcn_s_barrier();
        }

        const float inv = 1.0f / l_run;
        u16* yrow = &Y[(((size_t)b * T_SZ + q) * NH_SZ + h) * HD_SZ];
        for (int mi = 0; mi < 4; mi++) {
            uint2 pk2;
            pk2.x = cvt_pk_bf16(o[mi][0] * inv, o[mi][1] * inv);
            pk2.y = cvt_pk_bf16(o[mi][2] * inv, o[mi][3] * inv);
            *(uint2*)&yrow[mi * 16 + quad * 4] = pk2;
        }
    }
}

// ---------------- Proj GEMM: 128x128 tile, 512 thr, dbuf, counted vmcnt ----
#define PG_NT 16

__global__ __launch_bounds__(512, 4) void proj_gemm(const u16* __restrict__ Yin,
                                                    const u16* __restrict__ Wt,
                                                    const u16* __restrict__ pb,
                                                    void* __restrict__ out,
                                                    const int* __restrict__ flag) {
    __shared__ __align__(16) u16 As[2][128 * 64];   // 32 KB
    __shared__ __align__(16) u16 Bs[2][128 * 64];   // 32 KB
    const int isf = flag[0];
    const int bm = blockIdx.y * 128, bn = blockIdx.x * 128;
    const int tid = threadIdx.x;
    const int lane = tid & 63, w = tid >> 6;
    const int quad = lane >> 4, l16 = lane & 15;
    const int wm = (w & 3) * 32, wn = (w >> 2) * 64;   // 4M x 2N, per-wave 32x64
    const int lrow = lane >> 3;
    const int lcol = ((lane & 7) ^ lrow) * 8;         // swizzled source chunk
    const int sl0 = ((0 + quad) ^ (l16 & 7)) * 8;     // kk = 0
    const int sl1 = ((4 + quad) ^ (l16 & 7)) * 8;     // kk = 32

#define PG_STAGE(slot, kt) do {                                                  \
        const int k0_ = (kt) * 64;                                               \
        _Pragma("unroll")                                                        \
        for (int j = 0; j < 2; j++) {                                            \
            const int rb = w * 16 + j * 8;                                       \
            gl_lds16(&Yin[(size_t)(bm + rb + lrow) * K_DIM + k0_ + lcol],        \
                     &As[slot][rb * 64]);                                        \
            gl_lds16(&Wt[(size_t)(bn + rb + lrow) * K_DIM + k0_ + lcol],         \
                     &Bs[slot][rb * 64]);                                        \
        }                                                                        \
    } while (0)

    floatx4 acc[2][4];
#pragma unroll
    for (int mi = 0; mi < 2; mi++)
#pragma unroll
        for (int ni = 0; ni < 4; ni++) acc[mi][ni] = 0.f;

    // prologue: tiles 0 and 1 in flight (4 loads each); wait tile 0
    PG_STAGE(0, 0);
    PG_STAGE(1, 1);
    asm volatile("s_waitcnt vmcnt(4)" ::: "memory");
    __builtin_amdgcn_s_barrier();

    for (int t = 0; t < PG_NT; ++t) {
        const int cur = t & 1;
        const u16* as = As[cur];
        const u16* bs = Bs[cur];
        short8 a[2], b[4];
        // phase A: kk = 0
#pragma unroll
        for (int mi = 0; mi < 2; mi++)
            a[mi] = *(const short8*)&as[(wm + mi * 16 + l16) * 64 + sl0];
#pragma unroll
        for (int ni = 0; ni < 4; ni++)
            b[ni] = *(const short8*)&bs[(wn + ni * 16 + l16) * 64 + sl0];
        __builtin_amdgcn_s_setprio(1);
#pragma unroll
        for (int mi = 0; mi < 2; mi++)
#pragma unroll
            for (int ni = 0; ni < 4; ni++)
                acc[mi][ni] = __builtin_amdgcn_mfma_f32_16x16x32_bf16(
                    a[mi], b[ni], acc[mi][ni], 0, 0, 0);
        __builtin_amdgcn_s_setprio(0);
        // phase B reads: kk = 32
#pragma unroll
        for (int mi = 0; mi < 2; mi++)
            a[mi] = *(const short8*)&as[(wm + mi * 16 + l16) * 64 + sl1];
#pragma unroll
        for (int ni = 0; ni < 4; ni++)
            b[ni] = *(const short8*)&bs[(wn + ni * 16 + l16) * 64 + sl1];
        asm volatile("s_waitcnt lgkmcnt(0)" ::: "memory");
        __builtin_amdgcn_s_barrier();
        if (t < PG_NT - 1) {
            const int tn = (t + 2 < PG_NT) ? t + 2 : PG_NT - 1;
            PG_STAGE(cur, tn);
        }
        __builtin_amdgcn_s_setprio(1);
#pragma unroll
        for (int mi = 0; mi < 2; mi++)
#pragma unroll
            for (int ni = 0; ni < 4; ni++)
                acc[mi][ni] = __builtin_amdgcn_mfma_f32_16x16x32_bf16(
                    a[mi], b[ni], acc[mi][ni], 0, 0, 0);
        __builtin_amdgcn_s_setprio(0);
        asm volatile("s_waitcnt vmcnt(4)" ::: "memory");
        __builtin_amdgcn_s_barrier();
    }
#undef PG_STAGE

    for (int mi = 0; mi < 2; mi++) {
        for (int ni = 0; ni < 4; ni++) {
            const int col = bn + wn + ni * 16 + l16;
            const float bv = bf2f(pb[PB_BPROJ + col]);
            for (int r = 0; r < 4; r++) {
                const int row = bm + wm + mi * 16 + quad * 4 + r;
                const float v = acc[mi][ni][r] + bv;
                if (isf) ((float*)out)[(size_t)row * C_SZ + col] = v;
                else     ((u16*)out)[(size_t)row * C_SZ + col] = f2bf(v);
            }
        }
    }
}

extern "C" void kernel_launch(void* const* d_in, const int* in_sizes, int n_in,
                              void* d_out, int out_size, void* d_ws, size_t ws_size,
                              hipStream_t stream) {
    const void* x     = d_in[0];
    const void* Wqkv  = d_in[1];
    const void* bqkv  = d_in[2];
    const void* Wproj = d_in[3];
    const void* bproj = d_in[4];
    const void* qsc   = d_in[5];
    const void* qbi   = d_in[6];
    const void* ksc   = d_in[7];
    const void* kbi   = d_in[8];

    u16* ws = (u16*)d_ws;
    int* flag    = (int*)d_ws;
    u16* xb      = ws + OFF_XB;
    u16* Wt_qkv  = ws + OFF_WQT;
    u16* Wt_proj = ws + OFF_WPT;
    u16* pb      = ws + OFF_PB;
    u16* Qb      = ws + OFF_Q;
    u16* Kb      = ws + OFF_K;
    u16* Vb      = ws + OFF_V;     // [B,NH,HD,T]
    u16* Yb      = ws + OFF_Y;

    prep_k<<<12296, 256, 0, stream>>>(x, Wqkv, Wproj, bqkv, bproj,
                                      qsc, qbi, ksc, kbi,
                                      xb, Wt_qkv, Wt_proj, pb, flag);
    qkv_gemm<<<dim3(16, 64), 512, 0, stream>>>(xb, Wt_qkv, pb, Qb, Kb, Vb);
    attn_k<<<dim3(512), 512, 0, stream>>>(Qb, Kb, Vb, Yb);
    proj_gemm<<<dim3(8, 64), 512, 0, stream>>>(Yb, Wt_proj, pb, d_out, flag);
}

// Round 4
// 270.199 us; speedup vs baseline: 1.0511x; 1.0511x over previous
//
#include <hip/hip_runtime.h>
#include <hip/hip_bf16.h>

typedef unsigned short u16;
typedef __attribute__((ext_vector_type(8))) short short8;
typedef __attribute__((ext_vector_type(4))) float floatx4;

#define B_SZ 4
#define T_SZ 2048
#define C_SZ 1024
#define NH_SZ 16
#define HD_SZ 64
#define M_TOT 8192      // B*T
#define K_DIM 1024      // C

// fold softmax 1/sqrt(64) and log2(e) into Q's affine: scores land in log2 domain
#define QSCALE 0.1803368801111204f   // 0.125 * 1.4426950408889634

// workspace layout (u16 element offsets from ws base; all 16B-aligned)
#define OFF_XB   ((size_t)16)
#define OFF_WQT  (OFF_XB + 8388608)
#define OFF_WPT  (OFF_WQT + 3145728)
#define OFF_PB   (OFF_WPT + 1048576)
#define OFF_Q    (OFF_PB + 8192)
#define OFF_K    (OFF_Q + 8388608)
#define OFF_V    (OFF_K + 8388608)
#define OFF_Y    (OFF_V + 8388608)
// params sub-layout inside PB (contiguous: sources in order)
#define PB_BQKV  0
#define PB_BPROJ 3072
#define PB_QSC   4096
#define PB_QBI   5120
#define PB_KSC   6144
#define PB_KBI   7168

__device__ __forceinline__ float bf2f(u16 u) {
    return __uint_as_float(((unsigned)u) << 16);
}
__device__ __forceinline__ u16 f2bf(float f) {          // round-nearest-even
    unsigned x = __float_as_uint(f);
    unsigned r = (x + 0x7fffu + ((x >> 16) & 1u)) >> 16;
    return (u16)r;
}
__device__ __forceinline__ u16 f2bf_fast(float f) {     // round-half-up (cheap)
    return (u16)((__float_as_uint(f) + 0x8000u) >> 16);
}
// pack two f32 -> u32 of two bf16 (T12 recipe; no builtin on gfx950)
__device__ __forceinline__ unsigned cvt_pk_bf16(float lo, float hi) {
    unsigned r;
    asm("v_cvt_pk_bf16_f32 %0, %1, %2" : "=v"(r) : "v"(lo), "v"(hi));
    return r;
}
// async global->LDS, 16B per lane; LDS dest = wave-uniform base + lane*16
__device__ __forceinline__ void gl_lds16(const u16* g, u16* l) {
    __builtin_amdgcn_global_load_lds(
        (const __attribute__((address_space(1))) void*)g,
        (__attribute__((address_space(3))) void*)l, 16, 0, 0);
}
// wave-uniform dtype detect from x[0:128] u16 (deterministic across blocks)
__device__ __forceinline__ int detect_isf(const u16* xx, int lane) {
    float v0 = fabsf(bf2f(xx[lane * 2]));
    float v1 = fabsf(bf2f(xx[lane * 2 + 1]));
    int b0 = (v0 > 1024.0f) || (v0 != 0.0f && v0 < 9.5367431640625e-7f);
    int b1 = (v1 > 1024.0f) || (v1 != 0.0f && v1 < 9.5367431640625e-7f);
    unsigned long long ba = __ballot(b0), bb = __ballot(b1);
    return (__popcll(ba) + __popcll(bb)) > 8;
}

// ---- unified prep: x copy + params pack + both weight transposes ----------
__global__ __launch_bounds__(256) void prep_k(
        const void* __restrict__ x,
        const void* __restrict__ Wqkv, const void* __restrict__ Wproj,
        const void* __restrict__ bqkv, const void* __restrict__ bproj,
        const void* __restrict__ qsc, const void* __restrict__ qbi,
        const void* __restrict__ ksc, const void* __restrict__ kbi,
        u16* __restrict__ xb, u16* __restrict__ Wt_qkv,
        u16* __restrict__ Wt_proj, u16* __restrict__ pb,
        int* __restrict__ flag) {
    __shared__ u16 t[32][33];
    const int blk = blockIdx.x;
    const int isf = detect_isf((const u16*)x, threadIdx.x & 63);
    if (blk == 0 && threadIdx.x == 0) flag[0] = isf;
    if (blk < 8192) {                       // x -> xb (4 elems/thread)
        const int i = blk * 256 + threadIdx.x;
        if (isf) {
            const float4 v = ((const float4*)x)[i];
            ushort4 o;
            o.x = f2bf(v.x); o.y = f2bf(v.y); o.z = f2bf(v.z); o.w = f2bf(v.w);
            ((ushort4*)xb)[i] = o;
        } else {
            ((ushort4*)xb)[i] = ((const ushort4*)x)[i];
        }
        return;
    }
    if (blk < 8200) {                       // small params -> pb
        const int i4 = (blk - 8192) * 256 + threadIdx.x;
        if (i4 >= 2048) return;
        const int e = i4 * 4;
        const void* src; int off;
        if (e < 3072)      { src = bqkv;  off = e; }
        else if (e < 4096) { src = bproj; off = e - 3072; }
        else if (e < 5120) { src = qsc;   off = e - 4096; }
        else if (e < 6144) { src = qbi;   off = e - 5120; }
        else if (e < 7168) { src = ksc;   off = e - 6144; }
        else               { src = kbi;   off = e - 7168; }
        ushort4 o;
        if (isf) {
            const float4 v = *(const float4*)((const float*)src + off);
            o.x = f2bf(v.x); o.y = f2bf(v.y); o.z = f2bf(v.z); o.w = f2bf(v.w);
        } else {
            o = *(const ushort4*)((const u16*)src + off);
        }
        *(ushort4*)&pb[e] = o;
        return;
    }
    const void* in; u16* out; int R, C, idx;
    if (blk < 11272) { idx = blk - 8200;  in = Wqkv;  out = Wt_qkv;  R = 1024; C = 3072; }
    else             { idx = blk - 11272; in = Wproj; out = Wt_proj; R = 1024; C = 1024; }
    const int nbx = C >> 5;
    const int c0 = (idx % nbx) * 32, r0 = (idx / nbx) * 32;
    const int tx = threadIdx.x & 31, ty = threadIdx.x >> 5;  // ty in 0..7
    for (int i = 0; i < 4; i++) {
        int r = ty + i * 8;
        size_t gi = (size_t)(r0 + r) * C + c0 + tx;
        t[r][tx] = isf ? f2bf(((const float*)in)[gi]) : ((const u16*)in)[gi];
    }
    __syncthreads();
    for (int i = 0; i < 4; i++) {
        int cr = ty + i * 8;
        out[(size_t)(c0 + cr) * R + r0 + tx] = t[tx][cr];
    }
}

// ---------------- QKV GEMM: 128x192 tile, dbuf LDS (80KB -> 2 blocks/CU) ---
// 8 waves (2M x 4N), per-wave 64x48. Per K-tile per wave: 5 gl_lds (2 A + 3 B)
// -> steady-state guard s_waitcnt vmcnt(5).
#define QG_BM 128
#define QG_BN 192
#define QG_NT 16

__global__ __launch_bounds__(512, 4) void qkv_gemm(
        const u16* __restrict__ X, const u16* __restrict__ Wt,
        const u16* __restrict__ pb,
        u16* __restrict__ Qb, u16* __restrict__ Kb, u16* __restrict__ Vb) {
    __shared__ __align__(16) u16 As[2][QG_BM * 64];   // 32 KB
    __shared__ __align__(16) u16 Bs[2][QG_BN * 64];   // 48 KB
    const int bm = blockIdx.y * QG_BM, bn = blockIdx.x * QG_BN;
    const int tid = threadIdx.x;
    const int lane = tid & 63, w = tid >> 6;
    const int quad = lane >> 4, l16 = lane & 15;
    const int wm = (w >> 2) * 64;         // 0 or 64
    const int wn = (w & 3) * 48;          // 0,48,96,144
    const int lrow = lane >> 3;                       // 8 rows per inst
    const int lcol = ((lane & 7) ^ lrow) * 8;         // swizzled source chunk
    const int sl0 = ((0 + quad) ^ (l16 & 7)) * 8;     // kk = 0
    const int sl1 = ((4 + quad) ^ (l16 & 7)) * 8;     // kk = 32

#define QG_STAGE(slot, kt) do {                                                  \
        const int k0_ = (kt) * 64;                                               \
        _Pragma("unroll")                                                        \
        for (int j = 0; j < 2; j++) {                                            \
            const int rb = w * 16 + j * 8;                                       \
            gl_lds16(&X[(size_t)(bm + rb + lrow) * K_DIM + k0_ + lcol],          \
                     &As[slot][rb * 64]);                                        \
        }                                                                        \
        _Pragma("unroll")                                                        \
        for (int j = 0; j < 3; j++) {                                            \
            const int rb = w * 24 + j * 8;                                       \
            gl_lds16(&Wt[(size_t)(bn + rb + lrow) * K_DIM + k0_ + lcol],         \
                     &Bs[slot][rb * 64]);                                        \
        }                                                                        \
    } while (0)

    floatx4 acc[4][3];
#pragma unroll
    for (int mi = 0; mi < 4; mi++)
#pragma unroll
        for (int ni = 0; ni < 3; ni++) acc[mi][ni] = 0.f;

    // prologue: tiles 0 and 1 in flight; wait tile 0 (5 of tile 1 may remain)
    QG_STAGE(0, 0);
    QG_STAGE(1, 1);
    asm volatile("s_waitcnt vmcnt(5)" ::: "memory");
    __builtin_amdgcn_s_barrier();

    for (int t = 0; t < QG_NT; ++t) {
        const int cur = t & 1;
        const u16* as = As[cur];
        const u16* bs = Bs[cur];
        short8 a[4], b[3];
        // phase A: kk = 0
#pragma unroll
        for (int mi = 0; mi < 4; mi++)
            a[mi] = *(const short8*)&as[(wm + mi * 16 + l16) * 64 + sl0];
#pragma unroll
        for (int ni = 0; ni < 3; ni++)
            b[ni] = *(const short8*)&bs[(wn + ni * 16 + l16) * 64 + sl0];
        __builtin_amdgcn_s_setprio(1);
#pragma unroll
        for (int mi = 0; mi < 4; mi++)
#pragma unroll
            for (int ni = 0; ni < 3; ni++)
                acc[mi][ni] = __builtin_amdgcn_mfma_f32_16x16x32_bf16(
                    a[mi], b[ni], acc[mi][ni], 0, 0, 0);
        __builtin_amdgcn_s_setprio(0);
        // phase B reads: kk = 32
#pragma unroll
        for (int mi = 0; mi < 4; mi++)
            a[mi] = *(const short8*)&as[(wm + mi * 16 + l16) * 64 + sl1];
#pragma unroll
        for (int ni = 0; ni < 3; ni++)
            b[ni] = *(const short8*)&bs[(wn + ni * 16 + l16) * 64 + sl1];
        // all of this wave's reads of buf[cur] complete -> barrier -> overwrite
        asm volatile("s_waitcnt lgkmcnt(0)" ::: "memory");
        __builtin_amdgcn_s_barrier();
        if (t < QG_NT - 1) {
            const int tn = (t + 2 < QG_NT) ? t + 2 : QG_NT - 1;  // redundant at
            QG_STAGE(cur, tn);        // t=NT-2 keeps vmcnt accounting uniform
        }
        __builtin_amdgcn_s_setprio(1);
#pragma unroll
        for (int mi = 0; mi < 4; mi++)
#pragma unroll
            for (int ni = 0; ni < 3; ni++)
                acc[mi][ni] = __builtin_amdgcn_mfma_f32_16x16x32_bf16(
                    a[mi], b[ni], acc[mi][ni], 0, 0, 0);
        __builtin_amdgcn_s_setprio(0);
        // tile t+1 landed (only tile t+2's 5 loads may remain outstanding)
        asm volatile("s_waitcnt vmcnt(5)" ::: "memory");
        __builtin_amdgcn_s_barrier();
    }
#undef QG_STAGE

    const int bb = bm >> 11;   // batch index (BM=128 never crosses T=2048)
    const int tbase = bm & 2047;
#pragma unroll
    for (int ni = 0; ni < 3; ni++) {
        const int col = bn + wn + ni * 16 + l16;
        const int sec = col >> 10;          // wave-uniform per fragment
        const int cmod = col & 1023;
        const int h = cmod >> 6, d = cmod & 63;
        const float bv = bf2f(pb[PB_BQKV + col]);
        if (sec == 2) {
#pragma unroll
            for (int mi = 0; mi < 4; mi++) {
                const int t0 = tbase + wm + mi * 16 + quad * 4;
                ushort4 pk;
                pk.x = f2bf(acc[mi][ni][0] + bv);
                pk.y = f2bf(acc[mi][ni][1] + bv);
                pk.z = f2bf(acc[mi][ni][2] + bv);
                pk.w = f2bf(acc[mi][ni][3] + bv);
                *(ushort4*)&Vb[(((size_t)(bb * NH_SZ + h)) * HD_SZ + d) * T_SZ + t0] = pk;
            }
        } else {
            float sA, sB;
            if (sec == 0) {
                sA = bf2f(pb[PB_QSC + h * 64 + d]) * QSCALE;
                sB = bf2f(pb[PB_QBI + h * 64 + d]) * QSCALE;
            } else {
                sA = bf2f(pb[PB_KSC + h * 64 + d]);
                sB = bf2f(pb[PB_KBI + h * 64 + d]);
            }
            u16* dstbuf = (sec == 0) ? Qb : Kb;
#pragma unroll
            for (int mi = 0; mi < 4; mi++)
#pragma unroll
                for (int r = 0; r < 4; r++) {
                    const int tt = tbase + wm + mi * 16 + quad * 4 + r;
                    float v = (acc[mi][ni][r] + bv) * sA + sB;
                    dstbuf[(((size_t)(bb * NH_SZ + h)) * T_SZ + tt) * HD_SZ + d] = f2bf(v);
                }
        }
    }
}

// -------- Flash attention: 1 q-tile/block, 1024 blocks (LPT order), dbuf ---
// Grid re-sized so residency is LDS-limited (3 blocks/CU @ 51.2KB), not
// grid-limited (round-3 bug: 512 blocks = hard 2/CU cap).
// blk&63 = head (all 16 blocks of a head land on the same XCD), blk>>6
// ordered largest-qt-first for LPT makespan.
__global__ __launch_bounds__(512, 6) void attn_k(const u16* __restrict__ Qb,
                                                 const u16* __restrict__ Kb,
                                                 const u16* __restrict__ Vtg,
                                                 u16* __restrict__ Y) {
    __shared__ __align__(16) u16 Ks[2][64 * 64];    // [key][d], swizzled chunks
    __shared__ __align__(16) u16 Vs[2][64 * 64];    // [d][key], swizzled chunks
    __shared__ __align__(16) u16 Ps[8 * 16 * 72];   // per-wave P^T [q][key], stride 72
    const int blk = blockIdx.x;
    const int head = blk & 63;          // b*NH + h
    const int qt = 15 - (blk >> 6);     // largest q-tiles dispatch first
    const int b = head >> 4, h = head & 15;
    const int tid = threadIdx.x, lane = tid & 63, w = tid >> 6;
    const int quad = lane >> 4, l16 = lane & 15;
    const size_t qk_off = (size_t)head * (T_SZ * HD_SZ);
    const size_t v_off = (size_t)head * (HD_SZ * T_SZ);
    u16* psw = &Ps[w * 1152];           // wave-private P^T region
    const int lr = lane >> 3;                     // staging row within wave group
    const int lc = ((lane & 7) ^ lr) * 8;         // swizzled source chunk
    const int sl0 = ((quad) ^ (l16 & 7)) * 8;         // kk = 0
    const int sl1 = ((4 + quad) ^ (l16 & 7)) * 8;     // kk = 32

    short8 ones;
    for (int j = 0; j < 8; j++) ones[j] = (short)0x3F80;  // bf16 1.0

    const int q0 = qt * 128;
    const int rbase = q0 + w * 16;      // wave's first q row
    const int q = rbase + l16;          // this lane's q row
    const int nt = (q0 >> 6) + 2;       // k-tiles for this q-tile

    const short8 aq0 = *(const short8*)&Qb[qk_off + (size_t)q * HD_SZ + quad * 8];
    const short8 aq1 = *(const short8*)&Qb[qk_off + (size_t)q * HD_SZ + 32 + quad * 8];

    floatx4 o[4];                       // o^T: col=q(lane), rows=d-group mi
    for (int mi = 0; mi < 4; mi++) o[mi] = 0.f;
    float m_run = -1e30f, l_run = 0.f;

    // prologue: stage tile 0 into buf 0 (2 loads/wave in flight)
    gl_lds16(&Kb[qk_off + (size_t)(w * 8 + lr) * HD_SZ + lc], &Ks[0][w * 512]);
    gl_lds16(&Vtg[v_off + (size_t)(w * 8 + lr) * T_SZ + lc], &Vs[0][w * 512]);

    for (int t = 0; t < nt; ++t) {
        const int cur = t & 1;
        const int k0 = t * 64;
        if (t + 1 < nt) {               // prefetch tile t+1 into other buffer
            const int kn = k0 + 64;
            gl_lds16(&Kb[qk_off + (size_t)(kn + w * 8 + lr) * HD_SZ + lc],
                     &Ks[cur ^ 1][w * 512]);
            gl_lds16(&Vtg[v_off + (size_t)(w * 8 + lr) * T_SZ + kn + lc],
                     &Vs[cur ^ 1][w * 512]);
            // tile t landed; tile t+1's 2 loads may remain outstanding
            asm volatile("s_waitcnt vmcnt(2)" ::: "memory");
        } else {
            asm volatile("s_waitcnt vmcnt(0)" ::: "memory");
        }
        __builtin_amdgcn_s_barrier();

        if (k0 <= rbase + 15) {         // not fully masked for this wave
            const u16* ks = Ks[cur];
            const u16* vs = Vs[cur];
            floatx4 s[4];
            for (int ni = 0; ni < 4; ni++) s[ni] = 0.f;
            __builtin_amdgcn_s_setprio(1);
            for (int ni = 0; ni < 4; ni++)
                s[ni] = __builtin_amdgcn_mfma_f32_16x16x32_bf16(
                    *(const short8*)&ks[(ni * 16 + l16) * 64 + sl0], aq0, s[ni], 0, 0, 0);
            for (int ni = 0; ni < 4; ni++)
                s[ni] = __builtin_amdgcn_mfma_f32_16x16x32_bf16(
                    *(const short8*)&ks[(ni * 16 + l16) * 64 + sl1], aq1, s[ni], 0, 0, 0);
            __builtin_amdgcn_s_setprio(0);

            if (k0 + 63 > rbase) {          // tile touches the diagonal
                for (int ni = 0; ni < 4; ni++)
                    for (int r = 0; r < 4; r++) {
                        int key = k0 + ni * 16 + quad * 4 + r;
                        if (key > q) s[ni][r] = -1e30f;
                    }
            }

            // 3-ary max tree (fuses to v_max3_f32)
            float t0 = fmaxf(fmaxf(s[0][0], s[0][1]), s[0][2]);
            float t1 = fmaxf(fmaxf(s[0][3], s[1][0]), s[1][1]);
            float t2 = fmaxf(fmaxf(s[1][2], s[1][3]), s[2][0]);
            float t3 = fmaxf(fmaxf(s[2][1], s[2][2]), s[2][3]);
            float t4 = fmaxf(fmaxf(s[3][0], s[3][1]), s[3][2]);
            float mx = fmaxf(fmaxf(fmaxf(t0, t1), fmaxf(t2, t3)),
                             fmaxf(t4, s[3][3]));
            mx = fmaxf(mx, __shfl_xor(mx, 16, 64));
            mx = fmaxf(mx, __shfl_xor(mx, 32, 64));

            // defer-max (T13): skip rescale while max drift <= 8 (log2 units)
            if (!__all(mx <= m_run + 8.0f)) {
                const float mnew = fmaxf(m_run, mx);
                const float alpha = exp2f(m_run - mnew);
                m_run = mnew;
                for (int mi = 0; mi < 4; mi++) o[mi] *= alpha;
                l_run *= alpha;
            }
            for (int ni = 0; ni < 4; ni++)
                for (int r = 0; r < 4; r++)
                    s[ni][r] = exp2f(s[ni][r] - m_run);

            for (int ni = 0; ni < 4; ni++) {
                uint2 pp;
                pp.x = cvt_pk_bf16(s[ni][0], s[ni][1]);
                pp.y = cvt_pk_bf16(s[ni][2], s[ni][3]);
                *(uint2*)&psw[l16 * 72 + ni * 16 + quad * 4] = pp;
            }

            floatx4 s4 = 0.f;
            __builtin_amdgcn_s_setprio(1);
            for (int kk = 0; kk < 64; kk += 32) {
                short8 pfr = *(const short8*)&psw[l16 * 72 + kk + quad * 8];
                const int vsl = (kk == 0) ? sl0 : sl1;
                s4 = __builtin_amdgcn_mfma_f32_16x16x32_bf16(ones, pfr, s4, 0, 0, 0);
                for (int mi = 0; mi < 4; mi++) {
                    short8 vfr = *(const short8*)&vs[(mi * 16 + l16) * 64 + vsl];
                    o[mi] = __builtin_amdgcn_mfma_f32_16x16x32_bf16(vfr, pfr, o[mi], 0, 0, 0);
                }
            }
            __builtin_amdgcn_s_setprio(0);
            l_run += s4[0];
        }
        // all LDS reads of buf[cur] done before next iter's stage overwrites
        asm volatile("s_waitcnt lgkmcnt(0)" ::: "memory");
        __builtin_amdgcn_s_barrier();
    }

    const float inv = 1.0f / l_run;
    u16* yrow = &Y[(((size_t)b * T_SZ + q) * NH_SZ + h) * HD_SZ];
    for (int mi = 0; mi < 4; mi++) {
        uint2 pk2;
        pk2.x = cvt_pk_bf16(o[mi][0] * inv, o[mi][1] * inv);
        pk2.y = cvt_pk_bf16(o[mi][2] * inv, o[mi][3] * inv);
        *(uint2*)&yrow[mi * 16 + quad * 4] = pk2;
    }
}

// ---------------- Proj GEMM: 128x128 tile, 512 thr, dbuf, counted vmcnt ----
#define PG_NT 16

__global__ __launch_bounds__(512, 4) void proj_gemm(const u16* __restrict__ Yin,
                                                    const u16* __restrict__ Wt,
                                                    const u16* __restrict__ pb,
                                                    void* __restrict__ out,
                                                    const int* __restrict__ flag) {
    __shared__ __align__(16) u16 As[2][128 * 64];   // 32 KB
    __shared__ __align__(16) u16 Bs[2][128 * 64];   // 32 KB
    const int isf = flag[0];
    const int bm = blockIdx.y * 128, bn = blockIdx.x * 128;
    const int tid = threadIdx.x;
    const int lane = tid & 63, w = tid >> 6;
    const int quad = lane >> 4, l16 = lane & 15;
    const int wm = (w & 3) * 32, wn = (w >> 2) * 64;   // 4M x 2N, per-wave 32x64
    const int lrow = lane >> 3;
    const int lcol = ((lane & 7) ^ lrow) * 8;         // swizzled source chunk
    const int sl0 = ((0 + quad) ^ (l16 & 7)) * 8;     // kk = 0
    const int sl1 = ((4 + quad) ^ (l16 & 7)) * 8;     // kk = 32

#define PG_STAGE(slot, kt) do {                                                  \
        const int k0_ = (kt) * 64;                                               \
        _Pragma("unroll")                                                        \
        for (int j = 0; j < 2; j++) {                                            \
            const int rb = w * 16 + j * 8;                                       \
            gl_lds16(&Yin[(size_t)(bm + rb + lrow) * K_DIM + k0_ + lcol],        \
                     &As[slot][rb * 64]);                                        \
            gl_lds16(&Wt[(size_t)(bn + rb + lrow) * K_DIM + k0_ + lcol],         \
                     &Bs[slot][rb * 64]);                                        \
        }                                                                        \
    } while (0)

    floatx4 acc[2][4];
#pragma unroll
    for (int mi = 0; mi < 2; mi++)
#pragma unroll
        for (int ni = 0; ni < 4; ni++) acc[mi][ni] = 0.f;

    // prologue: tiles 0 and 1 in flight (4 loads each); wait tile 0
    PG_STAGE(0, 0);
    PG_STAGE(1, 1);
    asm volatile("s_waitcnt vmcnt(4)" ::: "memory");
    __builtin_amdgcn_s_barrier();

    for (int t = 0; t < PG_NT; ++t) {
        const int cur = t & 1;
        const u16* as = As[cur];
        const u16* bs = Bs[cur];
        short8 a[2], b[4];
        // phase A: kk = 0
#pragma unroll
        for (int mi = 0; mi < 2; mi++)
            a[mi] = *(const short8*)&as[(wm + mi * 16 + l16) * 64 + sl0];
#pragma unroll
        for (int ni = 0; ni < 4; ni++)
            b[ni] = *(const short8*)&bs[(wn + ni * 16 + l16) * 64 + sl0];
        __builtin_amdgcn_s_setprio(1);
#pragma unroll
        for (int mi = 0; mi < 2; mi++)
#pragma unroll
            for (int ni = 0; ni < 4; ni++)
                acc[mi][ni] = __builtin_amdgcn_mfma_f32_16x16x32_bf16(
                    a[mi], b[ni], acc[mi][ni], 0, 0, 0);
        __builtin_amdgcn_s_setprio(0);
        // phase B reads: kk = 32
#pragma unroll
        for (int mi = 0; mi < 2; mi++)
            a[mi] = *(const short8*)&as[(wm + mi * 16 + l16) * 64 + sl1];
#pragma unroll
        for (int ni = 0; ni < 4; ni++)
            b[ni] = *(const short8*)&bs[(wn + ni * 16 + l16) * 64 + sl1];
        asm volatile("s_waitcnt lgkmcnt(0)" ::: "memory");
        __builtin_amdgcn_s_barrier();
        if (t < PG_NT - 1) {
            const int tn = (t + 2 < PG_NT) ? t + 2 : PG_NT - 1;
            PG_STAGE(cur, tn);
        }
        __builtin_amdgcn_s_setprio(1);
#pragma unroll
        for (int mi = 0; mi < 2; mi++)
#pragma unroll
            for (int ni = 0; ni < 4; ni++)
                acc[mi][ni] = __builtin_amdgcn_mfma_f32_16x16x32_bf16(
                    a[mi], b[ni], acc[mi][ni], 0, 0, 0);
        __builtin_amdgcn_s_setprio(0);
        asm volatile("s_waitcnt vmcnt(4)" ::: "memory");
        __builtin_amdgcn_s_barrier();
    }
#undef PG_STAGE

    for (int mi = 0; mi < 2; mi++) {
        for (int ni = 0; ni < 4; ni++) {
            const int col = bn + wn + ni * 16 + l16;
            const float bv = bf2f(pb[PB_BPROJ + col]);
            for (int r = 0; r < 4; r++) {
                const int row = bm + wm + mi * 16 + quad * 4 + r;
                const float v = acc[mi][ni][r] + bv;
                if (isf) ((float*)out)[(size_t)row * C_SZ + col] = v;
                else     ((u16*)out)[(size_t)row * C_SZ + col] = f2bf(v);
            }
        }
    }
}

extern "C" void kernel_launch(void* const* d_in, const int* in_sizes, int n_in,
                              void* d_out, int out_size, void* d_ws, size_t ws_size,
                              hipStream_t stream) {
    const void* x     = d_in[0];
    const void* Wqkv  = d_in[1];
    const void* bqkv  = d_in[2];
    const void* Wproj = d_in[3];
    const void* bproj = d_in[4];
    const void* qsc   = d_in[5];
    const void* qbi   = d_in[6];
    const void* ksc   = d_in[7];
    const void* kbi   = d_in[8];

    u16* ws = (u16*)d_ws;
    int* flag    = (int*)d_ws;
    u16* xb      = ws + OFF_XB;
    u16* Wt_qkv  = ws + OFF_WQT;
    u16* Wt_proj = ws + OFF_WPT;
    u16* pb      = ws + OFF_PB;
    u16* Qb      = ws + OFF_Q;
    u16* Kb      = ws + OFF_K;
    u16* Vb      = ws + OFF_V;     // [B,NH,HD,T]
    u16* Yb      = ws + OFF_Y;

    prep_k<<<12296, 256, 0, stream>>>(x, Wqkv, Wproj, bqkv, bproj,
                                      qsc, qbi, ksc, kbi,
                                      xb, Wt_qkv, Wt_proj, pb, flag);
    qkv_gemm<<<dim3(16, 64), 512, 0, stream>>>(xb, Wt_qkv, pb, Qb, Kb, Vb);
    attn_k<<<dim3(1024), 512, 0, stream>>>(Qb, Kb, Vb, Yb);
    proj_gemm<<<dim3(8, 64), 512, 0, stream>>>(Yb, Wt_proj, pb, d_out, flag);
}